// Round 1
// baseline (597.267 us; speedup 1.0000x reference)
//
#include <hip/hip_runtime.h>
#include <math.h>

// Problem: B=8, C=512, H=W=64 -> HW=4096, Td=512. KV len = 1 -> softmax == 1
// -> attention out == v broadcast; rgb_t/dep_t are per-(b,c) constants.
// Only the losses read the big tensors; fused output is a per-(b,c) broadcast.
//
// R1: no same-line device atomics (150us XCD ping-pong).
// R2: nontemporal builtins need ext_vector types.
// R4: cooperative grid.sync is ~50us/sync on gfx950 -- never again.
// R6 structure (this round): the chain stages are PER-BATCH independent up to
// the gate pre-activation (BN is the only cross-batch op). So: 2 launches.
//   A: 8 per-batch chain blocks (4 __syncthreads-phased matvec stages in LDS)
//      + 1016 loss blocks reading the full 134MB (hides the ~12us chain).
//   B: 512 BN+sigmoid+broadcast blocks (67MB write, no redundant matvec)
//      + 1 reducer block (old k_final folded in).

#define BB 8
#define CC 512
#define TOTAL (8 * 512 * 4096)   // 16777216
#define N4 (TOTAL / 4)           // 4194304 f32x4
#define LOSSA 1016               // loss blocks in launch A
#define NP LOSSA                 // partial slots per loss type

typedef float f32x4 __attribute__((ext_vector_type(4)));

// One row-dot: all 64 lanes split K4 f32x4 chunks, butterfly leaves the full
// sum in every lane. x lives in LDS (pointer stays addrspace-inferable after
// forced inline).
__device__ __forceinline__ float wave_dot(const float* __restrict__ Wrow,
                                          const float* xlds, int K4, int lane)
{
    const f32x4* W4 = (const f32x4*)Wrow;
    const f32x4* x4 = (const f32x4*)xlds;
    float s = 0.0f;
    for (int t = lane; t < K4; t += 64) {
        f32x4 w = W4[t];
        f32x4 x = x4[t];
        s += w.x * x.x + w.y * x.y + w.z * x.z + w.w * x.w;
    }
    #pragma unroll
    for (int off = 32; off > 0; off >>= 1)
        s += __shfl_xor(s, off, 64);
    return s;
}

// Launch A: blocks 0..7 = per-batch chain through gate pre-activation;
// blocks 8..1023 = full loss read (134MB).
__global__ __launch_bounds__(512) void k_chain_loss(
    const float* __restrict__ text,
    const float* __restrict__ tp_w,  const float* __restrict__ tp_b,
    const float* __restrict__ rwqkv, const float* __restrict__ rbqkv,
    const float* __restrict__ dwqkv, const float* __restrict__ dbqkv,
    const float* __restrict__ rwo,   const float* __restrict__ rbo,
    const float* __restrict__ dwo,   const float* __restrict__ dbo,
    const float* __restrict__ gw,    const float* __restrict__ gb,
    float* __restrict__ pre, float* __restrict__ rd,
    const f32x4* __restrict__ rgb, const f32x4* __restrict__ dep,
    float* __restrict__ partials)
{
    const int lane = threadIdx.x & 63;
    const int wv   = threadIdx.x >> 6;           // 0..7
    if (blockIdx.x < BB) {
        __shared__ float bufA[1024];
        __shared__ float bufB[1024];
        const int b = blockIdx.x;
        // x0 = text[b]
        if (threadIdx.x < 512)
            bufA[threadIdx.x] = text[b * 512 + threadIdx.x];
        __syncthreads();
        // phase 1: tp = tp_w @ text_b + tp_b  -> bufB[0:512]
        for (int i = 0; i < 64; ++i) {
            const int o = (wv << 6) + i;
            float s = wave_dot(tp_w + (size_t)o * 512, bufA, 128, lane) + tp_b[o];
            if (lane == 0) bufB[o] = s;
        }
        __syncthreads();
        // phase 2: vr/vd = Wv @ tp + bv (Wv rows = qkv rows [1024,1536))
        for (int i = 0; i < 64; ++i) {
            const int o = (wv << 6) + i;
            float sr = wave_dot(rwqkv + (size_t)(1024 + o) * 512, bufB, 128, lane)
                       + rbqkv[1024 + o];
            float sd = wave_dot(dwqkv + (size_t)(1024 + o) * 512, bufB, 128, lane)
                       + dbqkv[1024 + o];
            if (lane == 0) { bufA[o] = sr; bufA[512 + o] = sd; }
        }
        __syncthreads();
        // phase 3: rdr/rdd = Wo @ v + bo  -> bufB and ws (for the mix in B)
        for (int i = 0; i < 64; ++i) {
            const int o = (wv << 6) + i;
            float sr = wave_dot(rwo + (size_t)o * 512, bufA, 128, lane) + rbo[o];
            float sd = wave_dot(dwo + (size_t)o * 512, bufA + 512, 128, lane) + dbo[o];
            if (lane == 0) {
                bufB[o] = sr; bufB[512 + o] = sd;
                rd[b * 1024 + o] = sr; rd[b * 1024 + 512 + o] = sd;
            }
        }
        __syncthreads();
        // phase 4: gate pre = gw @ [rdr;rdd] + gb  (K=1024) -> ws
        for (int i = 0; i < 64; ++i) {
            const int o = (wv << 6) + i;
            float s = wave_dot(gw + (size_t)o * 1024, bufB, 256, lane) + gb[o];
            if (lane == 0) pre[b * 512 + o] = s;
        }
    } else {
        const int lid = blockIdx.x - BB;         // 0..1015
        float ssq = 0.0f, sab = 0.0f;
        const int stride = LOSSA * 512;
        for (int j = lid * 512 + threadIdx.x; j < N4; j += stride) {
            f32x4 a  = __builtin_nontemporal_load(&rgb[j]);
            f32x4 b2 = __builtin_nontemporal_load(&dep[j]);
            float d0 = a.x - b2.x, d1 = a.y - b2.y;
            float d2 = a.z - b2.z, d3 = a.w - b2.w;
            ssq += d0 * d0 + d1 * d1 + d2 * d2 + d3 * d3;
            sab += fabsf(d0) + fabsf(d1) + fabsf(d2) + fabsf(d3);
        }
        #pragma unroll
        for (int off = 32; off > 0; off >>= 1) {
            ssq += __shfl_xor(ssq, off, 64);
            sab += __shfl_xor(sab, off, 64);
        }
        __shared__ float ls[16];
        if (lane == 0) { ls[wv] = ssq; ls[8 + wv] = sab; }
        __syncthreads();
        if (threadIdx.x == 0) {
            float a = 0.0f, c = 0.0f;
            #pragma unroll
            for (int k = 0; k < 8; ++k) { a += ls[k]; c += ls[8 + k]; }
            partials[lid] = a;
            partials[2048 + lid] = c;
        }
    }
}

// Launch B: blocks 0..511 = BN(batch) + sigmoid + mix + 67MB broadcast
// (block = 128 col-groups x 4 spatial quarters, wave = one channel o);
// block 512 = final reduce of the loss partials.
__global__ __launch_bounds__(256) void k_bcast_final(
    const float* __restrict__ pre, const float* __restrict__ rd,
    const float* __restrict__ bng, const float* __restrict__ bnb,
    f32x4* __restrict__ out, const float* __restrict__ partials,
    float* __restrict__ out_sc)
{
    const int lane = threadIdx.x & 63;
    if (blockIdx.x < 512) {
        const int g = blockIdx.x & 127;          // column group
        const int q = blockIdx.x >> 7;           // spatial quarter
        const int o = (g << 2) + (threadIdx.x >> 6);
        float pr[BB];
        float mean = 0.0f;
        #pragma unroll
        for (int b = 0; b < BB; ++b) { pr[b] = pre[b * 512 + o]; mean += pr[b]; }
        mean *= 0.125f;
        float var = 0.0f;
        #pragma unroll
        for (int b = 0; b < BB; ++b) { float dv = pr[b] - mean; var += dv * dv; }
        var *= 0.125f;
        float inv = rsqrtf(var + 1e-5f);
        float gg = bng[o], bb2 = bnb[o];
        #pragma unroll
        for (int b = 0; b < BB; ++b) {
            float xh = (pr[b] - mean) * inv;
            float z  = gg * xh + bb2;
            float gt = 1.0f / (1.0f + expf(-z));
            float rv = rd[b * 1024 + o];
            float dv = rd[b * 1024 + 512 + o];
            float f  = gt * rv + (1.0f - gt) * dv;
            f32x4 v  = {f, f, f, f};
            // f32x4 base: b*(512*4096/4) + o*(4096/4) + q*(1024/4)
            const int base = b * 524288 + o * 1024 + q * 256;
            #pragma unroll
            for (int i = 0; i < 4; ++i)
                __builtin_nontemporal_store(v, &out[base + i * 64 + lane]);
        }
    } else {
        float ssq = 0.0f, sab = 0.0f;
        for (int i = threadIdx.x; i < NP; i += 256) {
            ssq += partials[i];
            sab += partials[2048 + i];
        }
        #pragma unroll
        for (int off = 32; off > 0; off >>= 1) {
            ssq += __shfl_xor(ssq, off, 64);
            sab += __shfl_xor(sab, off, 64);
        }
        __shared__ float ls[8];
        const int wv = threadIdx.x >> 6;
        if (lane == 0) { ls[wv] = ssq; ls[4 + wv] = sab; }
        __syncthreads();
        if (threadIdx.x == 0) {
            const float invN = 1.0f / (float)TOTAL;
            out_sc[0] = (ls[0] + ls[1] + ls[2] + ls[3]) * invN;
            out_sc[1] = (ls[4] + ls[5] + ls[6] + ls[7]) * invN;
        }
    }
}

extern "C" void kernel_launch(void* const* d_in, const int* in_sizes, int n_in,
                              void* d_out, int out_size, void* d_ws, size_t ws_size,
                              hipStream_t stream) {
    const float* rgb   = (const float*)d_in[0];
    const float* dep   = (const float*)d_in[1];
    const float* text  = (const float*)d_in[2];
    const float* tp_w  = (const float*)d_in[3];
    const float* tp_b  = (const float*)d_in[4];
    const float* rwqkv = (const float*)d_in[5];
    const float* rbqkv = (const float*)d_in[6];
    const float* rwo   = (const float*)d_in[7];
    const float* rbo   = (const float*)d_in[8];
    const float* dwqkv = (const float*)d_in[9];
    const float* dbqkv = (const float*)d_in[10];
    const float* dwo   = (const float*)d_in[11];
    const float* dbo   = (const float*)d_in[12];
    const float* gw    = (const float*)d_in[13];
    const float* gb    = (const float*)d_in[14];
    const float* bng   = (const float*)d_in[15];
    const float* bnb   = (const float*)d_in[16];

    float* ws  = (float*)d_ws;
    float* pre = ws;              // 4096 (gate pre-activation, per b,o)
    float* rd  = ws + 4096;       // 8192 (rdr | rdd per batch)
    float* partials = ws + 12288; // ssq at +0, sab at +2048

    float* outf   = (float*)d_out;
    float* out_sc = outf + TOTAL;

    const f32x4* rgb4 = (const f32x4*)rgb;
    const f32x4* dep4 = (const f32x4*)dep;

    // A: full chain (8 per-batch blocks) + full 134MB loss read.
    k_chain_loss<<<BB + LOSSA, 512, 0, stream>>>(
        text, tp_w, tp_b, rwqkv, rbqkv, dwqkv, dbqkv,
        rwo, rbo, dwo, dbo, gw, gb, pre, rd, rgb4, dep4, partials);

    // B: BN + gate + 67MB broadcast + loss finalize.
    k_bcast_final<<<512 + 1, 256, 0, stream>>>(
        pre, rd, bng, bnb, (f32x4*)outf, partials, out_sc);
}

// Round 2
// 204.650 us; speedup vs baseline: 2.9185x; 2.9185x over previous
//
#include <hip/hip_runtime.h>
#include <math.h>

// Problem: B=8, C=512, H=W=64 -> HW=4096, Td=512. KV len = 1 -> softmax == 1
// -> attention out == v broadcast; rgb_t/dep_t are per-(b,c) constants.
// Only the losses read the big tensors; fused output is a per-(b,c) broadcast.
//
// R1: no same-line device atomics (150us XCD ping-pong).
// R2: nontemporal builtins need ext_vector types.
// R4: cooperative grid.sync is ~50us/sync on gfx950 -- never again.
// R5 structure: loss read (134MB) chunked INTO the chain-stage launches as
// extra blocks; launches ARE the global barriers between chain stages.
// R6 FAILED: concentrating the chain into 8 per-batch blocks (64 waves) made
// the weight loads latency-bound through 8 CUs -> 500us. Chain parallelism
// across 128 blocks/stage is mandatory; keep launch-per-stage.
// R7 (this round): stages 1-3 each carry a THIRD of the loss read (not a
// quarter), so all loss partials exist before the gate launch; the final
// scalar reduce folds into the gate launch as one extra block. 5 -> 4
// launches, and the gate launch sheds its 33.5MB loss read (write-only now).

#define BB 8
#define CC 512
#define TOTAL (8 * 512 * 4096)   // 16777216
#define N4 (TOTAL / 4)           // 4194304 f32x4
#define T1 1398102               // thirds boundaries in f32x4 units
#define T2 2796203
#define CHAINB 128               // chain blocks per stage launch
#define LOSSB_A 896              // loss blocks in each k_stage launch
#define NPART (3 * LOSSB_A)      // 2688 partial slots per loss type

typedef float f32x4 __attribute__((ext_vector_type(4)));

// Batched mat-vec: acc[b] = W_row . x[b]  (K multiple of 256, 16B-aligned).
// Butterfly reduction leaves the FULL total in ALL 64 lanes.
__device__ __forceinline__ void mv8(
    const float* __restrict__ Wrow, const float* __restrict__ x, int ldx,
    int K, int lane, float* acc)
{
    #pragma unroll
    for (int b = 0; b < BB; ++b) acc[b] = 0.0f;
    const f32x4* W4 = (const f32x4*)Wrow;
    const int K4 = K >> 2;
    for (int t = lane; t < K4; t += 64) {
        f32x4 w = W4[t];
        #pragma unroll
        for (int b = 0; b < BB; ++b) {
            f32x4 xv = ((const f32x4*)(x + b * ldx))[t];
            acc[b] += w.x * xv.x + w.y * xv.y + w.z * xv.z + w.w * xv.w;
        }
    }
    #pragma unroll
    for (int off = 32; off > 0; off >>= 1) {
        #pragma unroll
        for (int b = 0; b < BB; ++b)
            acc[b] += __shfl_xor(acc[b], off, 64);
    }
}

// Loss partial over f32x4 range [start, end), written to slot `pidx`.
__device__ __forceinline__ void loss_chunk(
    const f32x4* __restrict__ rgb, const f32x4* __restrict__ dep,
    int start, int end, int nblocks, int lid, float* __restrict__ partials,
    int pidx)
{
    const int stride = nblocks * 256;
    float ssq = 0.0f, sab = 0.0f;
    for (int j = start + lid * 256 + threadIdx.x; j < end; j += stride) {
        f32x4 a = __builtin_nontemporal_load(&rgb[j]);
        f32x4 b = __builtin_nontemporal_load(&dep[j]);
        float d0 = a.x - b.x, d1 = a.y - b.y, d2 = a.z - b.z, d3 = a.w - b.w;
        ssq += d0 * d0 + d1 * d1 + d2 * d2 + d3 * d3;
        sab += fabsf(d0) + fabsf(d1) + fabsf(d2) + fabsf(d3);
    }
    #pragma unroll
    for (int off = 32; off > 0; off >>= 1) {
        ssq += __shfl_xor(ssq, off, 64);
        sab += __shfl_xor(sab, off, 64);
    }
    __shared__ float ls[8];
    const int lane = threadIdx.x & 63;
    const int wv   = threadIdx.x >> 6;
    if (lane == 0) { ls[wv] = ssq; ls[4 + wv] = sab; }
    __syncthreads();
    if (threadIdx.x == 0) {
        partials[pidx]         = ls[0] + ls[1] + ls[2] + ls[3];
        partials[4096 + pidx]  = ls[4] + ls[5] + ls[6] + ls[7];
    }
}

// Chain stage (blocks 0..127) + loss third `stage-1` (blocks 128..1023).
__global__ __launch_bounds__(256) void k_stage(
    int stage,
    const float* __restrict__ text,
    const float* __restrict__ tp_w,  const float* __restrict__ tp_b,
    const float* __restrict__ rwqkv, const float* __restrict__ rbqkv,
    const float* __restrict__ dwqkv, const float* __restrict__ dbqkv,
    const float* __restrict__ rwo,   const float* __restrict__ rbo,
    const float* __restrict__ dwo,   const float* __restrict__ dbo,
    float* __restrict__ tp, float* __restrict__ vr, float* __restrict__ vd,
    float* __restrict__ rd,
    const f32x4* __restrict__ rgb, const f32x4* __restrict__ dep,
    float* __restrict__ partials)
{
    const int lane = threadIdx.x & 63;
    if (blockIdx.x < CHAINB) {
        const int w = (blockIdx.x << 2) + (threadIdx.x >> 6);  // 0..511
        float acc[BB];
        if (stage == 1) {
            mv8(tp_w + (size_t)w * 512, text, 512, 512, lane, acc);
            if (lane == 0) {
                float bs = tp_b[w];
                #pragma unroll
                for (int b = 0; b < BB; ++b) tp[b * 512 + w] = acc[b] + bs;
            }
        } else if (stage == 2) {
            mv8(rwqkv + (size_t)(1024 + w) * 512, tp, 512, 512, lane, acc);
            if (lane == 0) {
                float bs = rbqkv[1024 + w];
                #pragma unroll
                for (int b = 0; b < BB; ++b) vr[b * 512 + w] = acc[b] + bs;
            }
            mv8(dwqkv + (size_t)(1024 + w) * 512, tp, 512, 512, lane, acc);
            if (lane == 0) {
                float bs = dbqkv[1024 + w];
                #pragma unroll
                for (int b = 0; b < BB; ++b) vd[b * 512 + w] = acc[b] + bs;
            }
        } else {
            mv8(rwo + (size_t)w * 512, vr, 512, 512, lane, acc);
            if (lane == 0) {
                float bs = rbo[w];
                #pragma unroll
                for (int b = 0; b < BB; ++b) rd[b * 1024 + w] = acc[b] + bs;
            }
            mv8(dwo + (size_t)w * 512, vd, 512, 512, lane, acc);
            if (lane == 0) {
                float bs = dbo[w];
                #pragma unroll
                for (int b = 0; b < BB; ++b) rd[b * 1024 + 512 + w] = acc[b] + bs;
            }
        }
    } else {
        const int chunk = stage - 1;                // 0,1,2
        const int lid   = blockIdx.x - CHAINB;      // 0..895
        const int s0 = (chunk == 0) ? 0  : (chunk == 1) ? T1 : T2;
        const int e0 = (chunk == 0) ? T1 : (chunk == 1) ? T2 : N4;
        loss_chunk(rgb, dep, s0, e0, LOSSB_A, lid, partials,
                   chunk * LOSSB_A + lid);
    }
}

// Gate + BN(batch) + sigmoid + 67MB broadcast (blocks 0..511, 4x-redundant
// matvec: block = 128 col-groups x 4 spatial quarters) + final loss reduce
// (block 512).
__global__ __launch_bounds__(256) void k_gate_bcast(
    const float* __restrict__ gw,  const float* __restrict__ gb,
    const float* __restrict__ rd,
    const float* __restrict__ bng, const float* __restrict__ bnb,
    f32x4* __restrict__ out, const float* __restrict__ partials,
    float* __restrict__ out_sc)
{
    const int lane = threadIdx.x & 63;
    if (blockIdx.x < 512) {
        const int g = blockIdx.x & 127;             // column group
        const int q = blockIdx.x >> 7;              // spatial quarter
        const int o = (g << 2) + (threadIdx.x >> 6);
        float acc[BB];
        mv8(gw + (size_t)o * 1024, rd, 1024, 1024, lane, acc);
        // all lanes hold the full sums -> every lane computes fv identically
        float bsv = gb[o];
        float pre[BB];
        float mean = 0.0f;
        #pragma unroll
        for (int b = 0; b < BB; ++b) { pre[b] = acc[b] + bsv; mean += pre[b]; }
        mean *= 0.125f;
        float var = 0.0f;
        #pragma unroll
        for (int b = 0; b < BB; ++b) { float dv = pre[b] - mean; var += dv * dv; }
        var *= 0.125f;
        float inv = rsqrtf(var + 1e-5f);
        float gg = bng[o], bb2 = bnb[o];
        #pragma unroll
        for (int b = 0; b < BB; ++b) {
            float xh = (pre[b] - mean) * inv;
            float z  = gg * xh + bb2;
            float gt = 1.0f / (1.0f + expf(-z));
            float rv = rd[b * 1024 + o];
            float dv = rd[b * 1024 + 512 + o];
            float f  = gt * rv + (1.0f - gt) * dv;
            f32x4 v  = {f, f, f, f};
            // f32x4 base: b*(512*4096/4) + o*(4096/4) + q*(1024/4)
            const int base = b * 524288 + o * 1024 + q * 256;
            #pragma unroll
            for (int i = 0; i < 4; ++i)
                __builtin_nontemporal_store(v, &out[base + i * 64 + lane]);
        }
    } else {
        // Final reduce of all NPART partials -> two scalars. All partials
        // were produced by the three PRIOR stage launches.
        float ssq = 0.0f, sab = 0.0f;
        for (int i = threadIdx.x; i < NPART; i += 256) {
            ssq += partials[i];
            sab += partials[4096 + i];
        }
        #pragma unroll
        for (int off = 32; off > 0; off >>= 1) {
            ssq += __shfl_xor(ssq, off, 64);
            sab += __shfl_xor(sab, off, 64);
        }
        __shared__ float ls[8];
        const int wv = threadIdx.x >> 6;
        if (lane == 0) { ls[wv] = ssq; ls[4 + wv] = sab; }
        __syncthreads();
        if (threadIdx.x == 0) {
            const float invN = 1.0f / (float)TOTAL;
            out_sc[0] = (ls[0] + ls[1] + ls[2] + ls[3]) * invN;
            out_sc[1] = (ls[4] + ls[5] + ls[6] + ls[7]) * invN;
        }
    }
}

extern "C" void kernel_launch(void* const* d_in, const int* in_sizes, int n_in,
                              void* d_out, int out_size, void* d_ws, size_t ws_size,
                              hipStream_t stream) {
    const float* rgb   = (const float*)d_in[0];
    const float* dep   = (const float*)d_in[1];
    const float* text  = (const float*)d_in[2];
    const float* tp_w  = (const float*)d_in[3];
    const float* tp_b  = (const float*)d_in[4];
    const float* rwqkv = (const float*)d_in[5];
    const float* rbqkv = (const float*)d_in[6];
    const float* rwo   = (const float*)d_in[7];
    const float* rbo   = (const float*)d_in[8];
    const float* dwqkv = (const float*)d_in[9];
    const float* dbqkv = (const float*)d_in[10];
    const float* dwo   = (const float*)d_in[11];
    const float* dbo   = (const float*)d_in[12];
    const float* gw    = (const float*)d_in[13];
    const float* gb    = (const float*)d_in[14];
    const float* bng   = (const float*)d_in[15];
    const float* bnb   = (const float*)d_in[16];

    float* ws  = (float*)d_ws;
    float* tp  = ws;              // 4096
    float* vr  = ws + 4096;       // 4096
    float* vd  = ws + 8192;       // 4096
    float* rd  = ws + 12288;      // 8192
    float* partials = ws + 20480; // ssq at +0, sab at +4096

    float* outf   = (float*)d_out;
    float* out_sc = outf + TOTAL;

    const f32x4* rgb4 = (const f32x4*)rgb;
    const f32x4* dep4 = (const f32x4*)dep;

    // Chain stages 1..3, each carrying a THIRD of the loss read.
    for (int stage = 1; stage <= 3; ++stage) {
        k_stage<<<CHAINB + LOSSB_A, 256, 0, stream>>>(
            stage, text, tp_w, tp_b, rwqkv, rbqkv, dwqkv, dbqkv,
            rwo, rbo, dwo, dbo, tp, vr, vd, rd, rgb4, dep4, partials);
    }

    // Gate + broadcast + final scalar reduce (one extra block).
    k_gate_bcast<<<512 + 1, 256, 0, stream>>>(
        gw, gb, rd, bng, bnb, (f32x4*)outf, partials, out_sc);
}